// Round 6
// baseline (26276.721 us; speedup 1.0000x reference)
//
#include <hip/hip_runtime.h>
#include <math.h>

#define TC 64       // time chunk length
#define NCHUNK 8    // 512 / TC

// ---------------- math helpers ----------------
__device__ __forceinline__ float sigmoidf_(float x) { return 1.0f / (1.0f + __expf(-x)); }
__device__ __forceinline__ float tanhf_(float x) {
    float e = __expf(2.0f * x);
    return 1.0f - 2.0f / (e + 1.0f);
}

// relaxed agent-scope accessors (sc1 cache-bypassing, coherent at LLC)
__device__ __forceinline__ void st_agent_f32(float* p, float v) {
    __hip_atomic_store(p, v, __ATOMIC_RELAXED, __HIP_MEMORY_SCOPE_AGENT);
}
__device__ __forceinline__ unsigned long long ld_agent_u64(const unsigned long long* p) {
    return __hip_atomic_load(p, __ATOMIC_RELAXED, __HIP_MEMORY_SCOPE_AGENT);
}
__device__ __forceinline__ void st_agent_u32(unsigned* p, unsigned v) {
    __hip_atomic_store(p, v, __ATOMIC_RELAXED, __HIP_MEMORY_SCOPE_AGENT);
}
__device__ __forceinline__ unsigned ld_agent_u32(const unsigned* p) {
    return __hip_atomic_load(p, __ATOMIC_RELAXED, __HIP_MEMORY_SCOPE_AGENT);
}

// group flag wait: wave-0 lanes poll one flag each (64 flags per group)
__device__ __forceinline__ void flag_wait(const unsigned* base, unsigned tgt, int tid) {
    if (tid < 64) {
        int guard = 0;
        for (;;) {
            unsigned v = ld_agent_u32(&base[tid & 63]);
            if (__all((int)(v >= tgt))) break;
            __builtin_amdgcn_s_sleep(2);
            if (++guard > (1 << 18)) break;  // failsafe -> visible absmax failure
        }
    }
    __syncthreads();
}

// ---------------- bias prep: bs = b_ih + b_hh ----------------
__global__ __launch_bounds__(256) void prep_bias(
    const float* __restrict__ bi0, const float* __restrict__ bh0,
    const float* __restrict__ bi1, const float* __restrict__ bh1,
    float* __restrict__ bs0, float* __restrict__ bs1) {
    int i = blockIdx.x * 256 + threadIdx.x;
    if (i < 2048) {
        bs0[i] = bi0[i] + bh0[i];
        bs1[i] = bi1[i] + bh1[i];
    }
}

// ---------------- carry init ----------------
__global__ __launch_bounds__(256) void init_carry(
    const float* __restrict__ h0, const float* __restrict__ c0,
    float* __restrict__ hc0, float* __restrict__ cc0,
    float* __restrict__ hc1, float* __restrict__ cc1) {
    int i = blockIdx.x * 256 + threadIdx.x;
    if (i < 32768) {
        hc0[i] = h0[i];
        cc0[i] = c0[i];
        hc1[i] = h0[32768 + i];
        cc1[i] = c0[32768 + i];
    }
}

// ---------------- chunk GEMM (layer-0 input only): K=256 ----------------
template <int K>
__global__ __launch_bounds__(256) void gemm_xw(
    const float* __restrict__ A, const float* __restrict__ Bw,
    const float* __restrict__ bias, float* __restrict__ out,
    const int mode, const int t0) {
    __shared__ float As[16][128];
    __shared__ float Bs[16][128];
    const int tid = threadIdx.x;
    const int bm = blockIdx.y, bn = blockIdx.x;
    const int lrow = tid >> 1;
    const int lk0 = (tid & 1) * 8;
    const int grow = bm * 128 + lrow;
    const int arow = mode ? grow : ((grow >> 6) * 512 + t0 + (grow & 63));
    const float* Ap = A + (size_t)arow * K + lk0;
    const float* Bp = Bw + (size_t)(bn * 128 + lrow) * K + lk0;
    const int ty = tid >> 4, tx = tid & 15;

    float acc[8][8];
#pragma unroll
    for (int i = 0; i < 8; ++i)
#pragma unroll
        for (int j = 0; j < 8; ++j) acc[i][j] = 0.f;

    float4 pa0 = *(const float4*)(Ap);
    float4 pa1 = *(const float4*)(Ap + 4);
    float4 pb0 = *(const float4*)(Bp);
    float4 pb1 = *(const float4*)(Bp + 4);

    const int NT = K / 16;
    for (int ktile = 0; ktile < NT; ++ktile) {
#pragma unroll
        for (int c = 0; c < 4; ++c) {
            As[lk0 + c][lrow] = ((float*)&pa0)[c];
            As[lk0 + 4 + c][lrow] = ((float*)&pa1)[c];
            Bs[lk0 + c][lrow] = ((float*)&pb0)[c];
            Bs[lk0 + 4 + c][lrow] = ((float*)&pb1)[c];
        }
        __syncthreads();
        if (ktile + 1 < NT) {
            const float* Apn = Ap + (ktile + 1) * 16;
            const float* Bpn = Bp + (ktile + 1) * 16;
            pa0 = *(const float4*)(Apn);
            pa1 = *(const float4*)(Apn + 4);
            pb0 = *(const float4*)(Bpn);
            pb1 = *(const float4*)(Bpn + 4);
        }
#pragma unroll
        for (int kk = 0; kk < 16; ++kk) {
            const float4 a0 = *(const float4*)&As[kk][ty * 8];
            const float4 a1 = *(const float4*)&As[kk][ty * 8 + 4];
            const float4 b0 = *(const float4*)&Bs[kk][tx * 8];
            const float4 b1 = *(const float4*)&Bs[kk][tx * 8 + 4];
            const float av[8] = {a0.x, a0.y, a0.z, a0.w, a1.x, a1.y, a1.z, a1.w};
            const float bv[8] = {b0.x, b0.y, b0.z, b0.w, b1.x, b1.y, b1.z, b1.w};
#pragma unroll
            for (int i = 0; i < 8; ++i)
#pragma unroll
                for (int j = 0; j < 8; ++j) acc[i][j] = fmaf(av[i], bv[j], acc[i][j]);
        }
        __syncthreads();
    }

    const int col0 = bn * 128 + tx * 8;
    const float4 bv0 = *(const float4*)&bias[col0];
    const float4 bv1 = *(const float4*)&bias[col0 + 4];
    const float bb[8] = {bv0.x, bv0.y, bv0.z, bv0.w, bv1.x, bv1.y, bv1.z, bv1.w};
#pragma unroll
    for (int i = 0; i < 8; ++i) {
        int gr = bm * 128 + ty * 8 + i;
        int outr = mode ? gr : ((gr & 63) * 64 + (gr >> 6));
        float* op = out + (size_t)outr * 2048 + col0;
#pragma unroll
        for (int j = 0; j < 8; ++j) op[j] = acc[i][j] + bb[j];
    }
}

// ---------------- layer-pipelined persistent recurrence (one chunk) ----------------
// 512 WGs x 256 thr, 2/CU (64 KB LDS each). bid&1 = layer; bg = (bid>>1)&3
// (16 batches); js = bid>>3 (8 j's). Sync group = 64 WGs (all js, same layer+bg).
// L0: gates = xW0[t] + Whh0 @ h0(t);  publishes hseq slot t+1, flagsA.
// L1: gates = Wih1 @ h0(t+1) + Whh1 @ h1(t-1+1...) + bs1 (K=1024 fold, no GEMM);
//     waits flagsB(own, t+1) + flagsA(t+2); publishes h1pp slot (t+1)&1, flagsB.
// Thread: jt=tid>>5 (j), kt=tid&31. 64 accs (4g x 16b); 5-stage merge-exchange
// -> lane kt owns gate kt>>3 for batches 2*(kt&7), 2*(kt&7)+1; 8 width-32
// gathers; update x4-redundant; kt<8 lanes store.
__global__ __launch_bounds__(256, 2) void lstm_pipe(
    const float* __restrict__ xW,    // [TC][64][2048]
    const float* __restrict__ Whh0,  // [2048][512]
    const float* __restrict__ Wih1,  // [2048][512]
    const float* __restrict__ Whh1,  // [2048][512]
    const float* __restrict__ bs1,   // [2048]
    float* hcar0, float* ccar0, float* hcar1, float* ccar1,
    float* hseq,   // [TC+1][64][512]
    float* h1pp,   // [2][64][512]
    unsigned* flagsA, unsigned* flagsB, const int fb) {
    __shared__ float h4[16 * 1024];  // 64 KB
    const int tid = threadIdx.x;
    const int layer = blockIdx.x & 1;
    const int bg = (blockIdx.x >> 1) & 3;
    const int js = blockIdx.x >> 3;
    const int jt = tid >> 5, kt = tid & 31;
    const int j_cell = js * 8 + jt;
    const int g_own = kt >> 3;
    const int lb = kt & 7;
    const int b0 = bg * 16 + 2 * lb, b1 = b0 + 1;
    unsigned* gfA = flagsA + bg * 64;
    unsigned* gfB = flagsB + bg * 64;

    if (layer == 0) {
        // ---- W_hh0 slice in regs: 4 gates x 16 k (cols kt*16..kt*16+15) ----
        float4 W0[4][4];
#pragma unroll
        for (int g = 0; g < 4; ++g) {
            const float* wp = Whh0 + (size_t)(g * 512 + j_cell) * 512 + kt * 16;
#pragma unroll
            for (int q = 0; q < 4; ++q) W0[g][q] = *(const float4*)(wp + q * 4);
        }
        float c0r = ccar0[b0 * 512 + j_cell];
        float c1r = ccar0[b1 * 512 + j_cell];
        if (kt < 8) {  // publish slot-0 h0
            st_agent_f32(&hseq[b0 * 512 + j_cell], hcar0[b0 * 512 + j_cell]);
            st_agent_f32(&hseq[b1 * 512 + j_cell], hcar0[b1 * 512 + j_cell]);
        }
        __syncthreads();
        if (tid == 0) st_agent_u32(&gfA[js], (unsigned)(fb + 1));

        for (int r = 0; r < TC; ++r) {
            flag_wait(gfA, (unsigned)(fb + r + 1), tid);
            const float* hrd = hseq + (size_t)r * 32768;
#pragma unroll
            for (int i = 0; i < 16; ++i) {  // stage [16b][512] (f4-swizzled)
                int fid = tid + i * 256;
                int b = fid >> 8, k2 = fid & 255;
                unsigned long long v =
                    ld_agent_u64((const unsigned long long*)&hrd[(bg * 16 + b) * 512 + k2 * 2]);
                int s4 = b * 128 + (k2 >> 1);
                int ph = s4 ^ ((s4 >> 4) & 7);
                *(unsigned long long*)&h4[ph * 4 + (k2 & 1) * 2] = v;
            }
            __syncthreads();
            const float* xb = xW + (size_t)r * 131072;
            const float xw0 = xb[b0 * 2048 + g_own * 512 + j_cell];
            const float xw1 = xb[b1 * 2048 + g_own * 512 + j_cell];

            float a[64];
#pragma unroll
            for (int v = 0; v < 64; ++v) a[v] = 0.f;
#pragma unroll
            for (int q = 0; q < 4; ++q)
#pragma unroll
                for (int b = 0; b < 16; ++b) {
                    const int s4 = b * 128 + kt * 4 + q;
                    const float4 hv = *(const float4*)&h4[(s4 ^ ((s4 >> 4) & 7)) * 4];
#pragma unroll
                    for (int g = 0; g < 4; ++g) {
                        a[g * 16 + b] = fmaf(W0[g][q].x, hv.x, a[g * 16 + b]);
                        a[g * 16 + b] = fmaf(W0[g][q].y, hv.y, a[g * 16 + b]);
                        a[g * 16 + b] = fmaf(W0[g][q].z, hv.z, a[g * 16 + b]);
                        a[g * 16 + b] = fmaf(W0[g][q].w, hv.w, a[g * 16 + b]);
                    }
                }

            // 5-stage merge-exchange: 64 -> 2 (lane kt owns v=2kt, 2kt+1)
            float r0[32];
#pragma unroll
            for (int i = 0; i < 32; ++i) {
                float lo = a[i], hi = a[i + 32];
                float keep = (kt & 16) ? hi : lo, send = (kt & 16) ? lo : hi;
                r0[i] = keep + __shfl_xor(send, 16);
            }
            float r1[16];
#pragma unroll
            for (int i = 0; i < 16; ++i) {
                float lo = r0[i], hi = r0[i + 16];
                float keep = (kt & 8) ? hi : lo, send = (kt & 8) ? lo : hi;
                r1[i] = keep + __shfl_xor(send, 8);
            }
            float r2[8];
#pragma unroll
            for (int i = 0; i < 8; ++i) {
                float lo = r1[i], hi = r1[i + 8];
                float keep = (kt & 4) ? hi : lo, send = (kt & 4) ? lo : hi;
                r2[i] = keep + __shfl_xor(send, 4);
            }
            float r3[4];
#pragma unroll
            for (int i = 0; i < 4; ++i) {
                float lo = r2[i], hi = r2[i + 4];
                float keep = (kt & 2) ? hi : lo, send = (kt & 2) ? lo : hi;
                r3[i] = keep + __shfl_xor(send, 2);
            }
            float s0, s1;
            {
                float lo = r3[0], hi = r3[2];
                float keep = (kt & 1) ? hi : lo, send = (kt & 1) ? lo : hi;
                s0 = keep + __shfl_xor(send, 1);
                lo = r3[1]; hi = r3[3];
                keep = (kt & 1) ? hi : lo; send = (kt & 1) ? lo : hi;
                s1 = keep + __shfl_xor(send, 1);
            }
            s0 += xw0;
            s1 += xw1;

            const float i0 = __shfl(s0, lb, 32), f0 = __shfl(s0, 8 + lb, 32);
            const float g0v = __shfl(s0, 16 + lb, 32), o0 = __shfl(s0, 24 + lb, 32);
            const float i1 = __shfl(s1, lb, 32), f1 = __shfl(s1, 8 + lb, 32);
            const float g1v = __shfl(s1, 16 + lb, 32), o1 = __shfl(s1, 24 + lb, 32);
            c0r = sigmoidf_(f0) * c0r + sigmoidf_(i0) * tanhf_(g0v);
            const float hn0 = sigmoidf_(o0) * tanhf_(c0r);
            c1r = sigmoidf_(f1) * c1r + sigmoidf_(i1) * tanhf_(g1v);
            const float hn1 = sigmoidf_(o1) * tanhf_(c1r);
            if (kt < 8) {
                float* hw = hseq + (size_t)(r + 1) * 32768;
                st_agent_f32(&hw[b0 * 512 + j_cell], hn0);
                st_agent_f32(&hw[b1 * 512 + j_cell], hn1);
                if (r == TC - 1) {
                    hcar0[b0 * 512 + j_cell] = hn0;
                    hcar0[b1 * 512 + j_cell] = hn1;
                    ccar0[b0 * 512 + j_cell] = c0r;
                    ccar0[b1 * 512 + j_cell] = c1r;
                }
            }
            __syncthreads();
            if (tid == 0) st_agent_u32(&gfA[js], (unsigned)(fb + r + 2));
        }
    } else {
        // ---- Wih1 + Whh1 slices in regs (K=1024 fold) ----
        float4 Wi[4][4], Wh[4][4];
#pragma unroll
        for (int g = 0; g < 4; ++g) {
            const float* wi = Wih1 + (size_t)(g * 512 + j_cell) * 512 + kt * 16;
            const float* wh = Whh1 + (size_t)(g * 512 + j_cell) * 512 + kt * 16;
#pragma unroll
            for (int q = 0; q < 4; ++q) {
                Wi[g][q] = *(const float4*)(wi + q * 4);
                Wh[g][q] = *(const float4*)(wh + q * 4);
            }
        }
        const float bias = bs1[g_own * 512 + j_cell];
        float c0r = ccar1[b0 * 512 + j_cell];
        float c1r = ccar1[b1 * 512 + j_cell];
        if (kt < 8) {  // publish h1 slot 0
            st_agent_f32(&h1pp[b0 * 512 + j_cell], hcar1[b0 * 512 + j_cell]);
            st_agent_f32(&h1pp[b1 * 512 + j_cell], hcar1[b1 * 512 + j_cell]);
        }
        __syncthreads();
        if (tid == 0) st_agent_u32(&gfB[js], (unsigned)(fb + 1));

        for (int t = 0; t < TC; ++t) {
            flag_wait(gfB, (unsigned)(fb + t + 1), tid);  // own h1(t) published
            flag_wait(gfA, (unsigned)(fb + t + 2), tid);  // h0 slot t+1 ready
            const float* h0rd = hseq + (size_t)(t + 1) * 32768;
            const float* h1rd = h1pp + (size_t)(t & 1) * 32768;
#pragma unroll
            for (int i = 0; i < 16; ++i) {  // h0 -> half 0
                int fid = tid + i * 256;
                int b = fid >> 8, k2 = fid & 255;
                unsigned long long v =
                    ld_agent_u64((const unsigned long long*)&h0rd[(bg * 16 + b) * 512 + k2 * 2]);
                int s4 = b * 256 + (k2 >> 1);
                int ph = s4 ^ ((s4 >> 4) & 7);
                *(unsigned long long*)&h4[ph * 4 + (k2 & 1) * 2] = v;
            }
#pragma unroll
            for (int i = 0; i < 16; ++i) {  // h1 -> half 1
                int fid = tid + i * 256;
                int b = fid >> 8, k2 = fid & 255;
                unsigned long long v =
                    ld_agent_u64((const unsigned long long*)&h1rd[(bg * 16 + b) * 512 + k2 * 2]);
                int s4 = b * 256 + 128 + (k2 >> 1);
                int ph = s4 ^ ((s4 >> 4) & 7);
                *(unsigned long long*)&h4[ph * 4 + (k2 & 1) * 2] = v;
            }
            __syncthreads();

            float a[64];
#pragma unroll
            for (int v = 0; v < 64; ++v) a[v] = 0.f;
#pragma unroll
            for (int q = 0; q < 4; ++q)
#pragma unroll
                for (int b = 0; b < 16; ++b) {
                    const int s4 = b * 256 + kt * 4 + q;
                    const float4 hv = *(const float4*)&h4[(s4 ^ ((s4 >> 4) & 7)) * 4];
#pragma unroll
                    for (int g = 0; g < 4; ++g) {
                        a[g * 16 + b] = fmaf(Wi[g][q].x, hv.x, a[g * 16 + b]);
                        a[g * 16 + b] = fmaf(Wi[g][q].y, hv.y, a[g * 16 + b]);
                        a[g * 16 + b] = fmaf(Wi[g][q].z, hv.z, a[g * 16 + b]);
                        a[g * 16 + b] = fmaf(Wi[g][q].w, hv.w, a[g * 16 + b]);
                    }
                }
#pragma unroll
            for (int q = 0; q < 4; ++q)
#pragma unroll
                for (int b = 0; b < 16; ++b) {
                    const int s4 = b * 256 + 128 + kt * 4 + q;
                    const float4 hv = *(const float4*)&h4[(s4 ^ ((s4 >> 4) & 7)) * 4];
#pragma unroll
                    for (int g = 0; g < 4; ++g) {
                        a[g * 16 + b] = fmaf(Wh[g][q].x, hv.x, a[g * 16 + b]);
                        a[g * 16 + b] = fmaf(Wh[g][q].y, hv.y, a[g * 16 + b]);
                        a[g * 16 + b] = fmaf(Wh[g][q].z, hv.z, a[g * 16 + b]);
                        a[g * 16 + b] = fmaf(Wh[g][q].w, hv.w, a[g * 16 + b]);
                    }
                }

            float r0[32];
#pragma unroll
            for (int i = 0; i < 32; ++i) {
                float lo = a[i], hi = a[i + 32];
                float keep = (kt & 16) ? hi : lo, send = (kt & 16) ? lo : hi;
                r0[i] = keep + __shfl_xor(send, 16);
            }
            float r1[16];
#pragma unroll
            for (int i = 0; i < 16; ++i) {
                float lo = r0[i], hi = r0[i + 16];
                float keep = (kt & 8) ? hi : lo, send = (kt & 8) ? lo : hi;
                r1[i] = keep + __shfl_xor(send, 8);
            }
            float r2[8];
#pragma unroll
            for (int i = 0; i < 8; ++i) {
                float lo = r1[i], hi = r1[i + 8];
                float keep = (kt & 4) ? hi : lo, send = (kt & 4) ? lo : hi;
                r2[i] = keep + __shfl_xor(send, 4);
            }
            float r3[4];
#pragma unroll
            for (int i = 0; i < 4; ++i) {
                float lo = r2[i], hi = r2[i + 4];
                float keep = (kt & 2) ? hi : lo, send = (kt & 2) ? lo : hi;
                r3[i] = keep + __shfl_xor(send, 2);
            }
            float s0, s1;
            {
                float lo = r3[0], hi = r3[2];
                float keep = (kt & 1) ? hi : lo, send = (kt & 1) ? lo : hi;
                s0 = keep + __shfl_xor(send, 1);
                lo = r3[1]; hi = r3[3];
                keep = (kt & 1) ? hi : lo; send = (kt & 1) ? lo : hi;
                s1 = keep + __shfl_xor(send, 1);
            }
            s0 += bias;
            s1 += bias;

            const float i0 = __shfl(s0, lb, 32), f0 = __shfl(s0, 8 + lb, 32);
            const float g0v = __shfl(s0, 16 + lb, 32), o0 = __shfl(s0, 24 + lb, 32);
            const float i1 = __shfl(s1, lb, 32), f1 = __shfl(s1, 8 + lb, 32);
            const float g1v = __shfl(s1, 16 + lb, 32), o1 = __shfl(s1, 24 + lb, 32);
            c0r = sigmoidf_(f0) * c0r + sigmoidf_(i0) * tanhf_(g0v);
            const float hn0 = sigmoidf_(o0) * tanhf_(c0r);
            c1r = sigmoidf_(f1) * c1r + sigmoidf_(i1) * tanhf_(g1v);
            const float hn1 = sigmoidf_(o1) * tanhf_(c1r);
            if (kt < 8) {
                float* hw = h1pp + (size_t)((t + 1) & 1) * 32768;
                st_agent_f32(&hw[b0 * 512 + j_cell], hn0);
                st_agent_f32(&hw[b1 * 512 + j_cell], hn1);
                if (t == TC - 1) {
                    hcar1[b0 * 512 + j_cell] = hn0;
                    hcar1[b1 * 512 + j_cell] = hn1;
                    ccar1[b0 * 512 + j_cell] = c0r;
                    ccar1[b1 * 512 + j_cell] = c1r;
                }
            }
            __syncthreads();
            if (tid == 0) st_agent_u32(&gfB[js], (unsigned)(fb + t + 2));
        }
    }
}

// ---------------- FC head ----------------
__global__ __launch_bounds__(256) void fc_kernel(
    const float* __restrict__ h, const float* __restrict__ Wfc,
    const float* __restrict__ bfc, float* __restrict__ out) {
    int gid = blockIdx.x * 256 + threadIdx.x;  // 0..8191
    int b = gid >> 7, cc = gid & 127;
    const float* hr = h + b * 512;
    const float* wr = Wfc + cc * 512;
    float s = 0.f;
#pragma unroll 4
    for (int k = 0; k < 512; k += 4) {
        float4 hv = *(const float4*)(hr + k);
        float4 wv = *(const float4*)(wr + k);
        s += hv.x * wv.x + hv.y * wv.y + hv.z * wv.z + hv.w * wv.w;
    }
    out[gid] = s + bfc[cc];
}

// ---------------- launch ----------------
extern "C" void kernel_launch(void* const* d_in, const int* in_sizes, int n_in,
                              void* d_out, int out_size, void* d_ws, size_t ws_size,
                              hipStream_t stream) {
    const float* x = (const float*)d_in[0];
    const float* h0 = (const float*)d_in[1];
    const float* c0 = (const float*)d_in[2];
    const float* Wih0 = (const float*)d_in[3];
    const float* Whh0 = (const float*)d_in[4];
    const float* bih0 = (const float*)d_in[5];
    const float* bhh0 = (const float*)d_in[6];
    const float* Wih1 = (const float*)d_in[7];
    const float* Whh1 = (const float*)d_in[8];
    const float* bih1 = (const float*)d_in[9];
    const float* bhh1 = (const float*)d_in[10];
    const float* Wfc = (const float*)d_in[11];
    const float* bfc = (const float*)d_in[12];

    // workspace layout (~42 MB total)
    char* ws = (char*)d_ws;
    size_t off = 0;
    float* xWc = (float*)(ws + off); off += (size_t)TC * 64 * 2048 * 4;      // 33,554,432
    float* hseqc = (float*)(ws + off); off += (size_t)(TC + 1) * 32768 * 4;  //  8,519,680
    float* h1pp = (float*)(ws + off); off += 2 * 32768 * 4;                  //    262,144
    float* hcar0 = (float*)(ws + off); off += 32768 * 4;
    float* ccar0 = (float*)(ws + off); off += 32768 * 4;
    float* hcar1 = (float*)(ws + off); off += 32768 * 4;
    float* ccar1 = (float*)(ws + off); off += 32768 * 4;
    float* bs0 = (float*)(ws + off); off += 2048 * 4;
    float* bs1 = (float*)(ws + off); off += 2048 * 4;
    unsigned* flagsA = (unsigned*)(ws + off); off += 4 * 64 * 4;  // [bg][js]
    unsigned* flagsB = (unsigned*)(ws + off); off += 4 * 64 * 4;

    prep_bias<<<8, 256, 0, stream>>>(bih0, bhh0, bih1, bhh1, bs0, bs1);
    init_carry<<<128, 256, 0, stream>>>(h0, c0, hcar0, ccar0, hcar1, ccar1);
    hipMemsetAsync(flagsA, 0, 2 * 4 * 64 * 4, stream);

    const dim3 gg(16, 32);
    for (int k = 0; k < NCHUNK; ++k) {
        // layer-0 input GEMM for chunk k: xWc[t][b][2048]
        gemm_xw<256><<<gg, 256, 0, stream>>>(x, Wih0, bs0, xWc, 0, k * TC);
        // both layers, pipelined (L1 lags L0 by one step; no layer-1 GEMM)
        lstm_pipe<<<512, 256, 0, stream>>>(xWc, Whh0, Wih1, Whh1, bs1,
                                           hcar0, ccar0, hcar1, ccar1,
                                           hseqc, h1pp, flagsA, flagsB, k * (TC + 1));
    }
    // FC on final layer-1 hidden state
    fc_kernel<<<32, 256, 0, stream>>>(hcar1, Wfc, bfc, (float*)d_out);
}

// Round 9
// 7096.676 us; speedup vs baseline: 3.7027x; 3.7027x over previous
//
#include <hip/hip_runtime.h>
#include <math.h>

#define TC 64       // time chunk length
#define NCHUNK 8    // 512 / TC
#define NGW 32      // workgroups per sync group (one per j-slice of 16)

// ---------------- math helpers ----------------
__device__ __forceinline__ float sigmoidf_(float x) { return 1.0f / (1.0f + __expf(-x)); }
__device__ __forceinline__ float tanhf_(float x) {
    float e = __expf(2.0f * x);
    return 1.0f - 2.0f / (e + 1.0f);
}

// relaxed agent-scope accessors — the PROVEN round-5 semantics. Do not replace
// with hand-rolled sc0/sc1 asm: rounds 7-8 showed the compiler's encoding is
// not reproducible from documented flags alone (sparse stale-h absmax 4e-3).
__device__ __forceinline__ void st_agent_f32(float* p, float v) {
    __hip_atomic_store(p, v, __ATOMIC_RELAXED, __HIP_MEMORY_SCOPE_AGENT);
}
__device__ __forceinline__ unsigned long long ld_agent_u64(const unsigned long long* p) {
    return __hip_atomic_load(p, __ATOMIC_RELAXED, __HIP_MEMORY_SCOPE_AGENT);
}
__device__ __forceinline__ void st_agent_u32(unsigned* p, unsigned v) {
    __hip_atomic_store(p, v, __ATOMIC_RELAXED, __HIP_MEMORY_SCOPE_AGENT);
}
__device__ __forceinline__ unsigned ld_agent_u32(const unsigned* p) {
    return __hip_atomic_load(p, __ATOMIC_RELAXED, __HIP_MEMORY_SCOPE_AGENT);
}

// ---------------- bias prep ----------------
__global__ __launch_bounds__(256) void prep_bias(
    const float* __restrict__ bi0, const float* __restrict__ bh0,
    const float* __restrict__ bi1, const float* __restrict__ bh1,
    float* __restrict__ bs0, float* __restrict__ bs1) {
    int i = blockIdx.x * 256 + threadIdx.x;
    if (i < 2048) {
        bs0[i] = bi0[i] + bh0[i];
        bs1[i] = bi1[i] + bh1[i];
    }
}

// ---------------- carry init ----------------
__global__ __launch_bounds__(256) void init_carry(
    const float* __restrict__ h0, const float* __restrict__ c0,
    float* __restrict__ hc0, float* __restrict__ cc0,
    float* __restrict__ hc1, float* __restrict__ cc1) {
    int i = blockIdx.x * 256 + threadIdx.x;
    if (i < 32768) {
        hc0[i] = h0[i];
        cc0[i] = c0[i];
        hc1[i] = h0[32768 + i];
        cc1[i] = c0[32768 + i];
    }
}

// ---------------- chunk GEMM (proven round-5 kernel, unchanged) ----------------
template <int K>
__global__ __launch_bounds__(256) void gemm_xw(
    const float* __restrict__ A, const float* __restrict__ Bw,
    const float* __restrict__ bias, float* __restrict__ out,
    const int mode, const int t0) {
    __shared__ float As[16][128];
    __shared__ float Bs[16][128];
    const int tid = threadIdx.x;
    const int bm = blockIdx.y, bn = blockIdx.x;
    const int lrow = tid >> 1;
    const int lk0 = (tid & 1) * 8;
    const int grow = bm * 128 + lrow;
    const int arow = mode ? grow : ((grow >> 6) * 512 + t0 + (grow & 63));
    const float* Ap = A + (size_t)arow * K + lk0;
    const float* Bp = Bw + (size_t)(bn * 128 + lrow) * K + lk0;
    const int ty = tid >> 4, tx = tid & 15;

    float acc[8][8];
#pragma unroll
    for (int i = 0; i < 8; ++i)
#pragma unroll
        for (int j = 0; j < 8; ++j) acc[i][j] = 0.f;

    float4 pa0 = *(const float4*)(Ap);
    float4 pa1 = *(const float4*)(Ap + 4);
    float4 pb0 = *(const float4*)(Bp);
    float4 pb1 = *(const float4*)(Bp + 4);

    const int NT = K / 16;
    for (int ktile = 0; ktile < NT; ++ktile) {
#pragma unroll
        for (int c = 0; c < 4; ++c) {
            As[lk0 + c][lrow] = ((float*)&pa0)[c];
            As[lk0 + 4 + c][lrow] = ((float*)&pa1)[c];
            Bs[lk0 + c][lrow] = ((float*)&pb0)[c];
            Bs[lk0 + 4 + c][lrow] = ((float*)&pb1)[c];
        }
        __syncthreads();
        if (ktile + 1 < NT) {
            const float* Apn = Ap + (ktile + 1) * 16;
            const float* Bpn = Bp + (ktile + 1) * 16;
            pa0 = *(const float4*)(Apn);
            pa1 = *(const float4*)(Apn + 4);
            pb0 = *(const float4*)(Bpn);
            pb1 = *(const float4*)(Bpn + 4);
        }
#pragma unroll
        for (int kk = 0; kk < 16; ++kk) {
            const float4 a0 = *(const float4*)&As[kk][ty * 8];
            const float4 a1 = *(const float4*)&As[kk][ty * 8 + 4];
            const float4 b0 = *(const float4*)&Bs[kk][tx * 8];
            const float4 b1 = *(const float4*)&Bs[kk][tx * 8 + 4];
            const float av[8] = {a0.x, a0.y, a0.z, a0.w, a1.x, a1.y, a1.z, a1.w};
            const float bv[8] = {b0.x, b0.y, b0.z, b0.w, b1.x, b1.y, b1.z, b1.w};
#pragma unroll
            for (int i = 0; i < 8; ++i)
#pragma unroll
                for (int j = 0; j < 8; ++j) acc[i][j] = fmaf(av[i], bv[j], acc[i][j]);
        }
        __syncthreads();
    }

    const int col0 = bn * 128 + tx * 8;
    const float4 bv0 = *(const float4*)&bias[col0];
    const float4 bv1 = *(const float4*)&bias[col0 + 4];
    const float bb[8] = {bv0.x, bv0.y, bv0.z, bv0.w, bv1.x, bv1.y, bv1.z, bv1.w};
#pragma unroll
    for (int i = 0; i < 8; ++i) {
        int gr = bm * 128 + ty * 8 + i;
        int outr = mode ? gr : ((gr & 63) * 64 + (gr >> 6));
        float* op = out + (size_t)outr * 2048 + col0;
#pragma unroll
        for (int j = 0; j < 8; ++j) op[j] = acc[i][j] + bb[j];
    }
}

// ---------------- persistent LSTM recurrence over one TC chunk ----------------
// 256 WGs x 512 threads, 1 WG/CU. WG: js = bid>>3 (16 j's), bb = bid&7.
// Sync group = 32 WGs sharing bb (XCD-local under round-robin bid->XCD; this
// is a perf heuristic only — agent-scope atomics are correct regardless).
// Thread (jt = tid>>5 in 0..15, kt = tid&31): j = js*16+jt, k in [kt*16,+16).
// W_hh slice in regs (64 f/thread). 32 accs [4g][8b]; 5-stage merge-exchange
// -> lane kt owns (g=kt>>3, b=kt&7); 4 width-32 gathers; update x4-redundant.
// xW(t+1) prefetched into a register during step t's MACs (off critical path).
__global__ __launch_bounds__(512, 2) void lstm_rec(
    const float* __restrict__ xW,   // [TC][64][2048]
    const float* __restrict__ Whh,  // [2048][512]
    float* hcar, float* ccar,
    float* hbuf, const int full_seq, unsigned* flags, const int fbase) {
    __shared__ float h4[8 * 512];  // 16 KB, f4-slot XOR swizzled
    const int tid = threadIdx.x;
    const int js = blockIdx.x >> 3;  // 0..31
    const int bb = blockIdx.x & 7;
    const int jt = tid >> 5, kt = tid & 31;
    const int j_cell = js * 16 + jt;
    const int b_own = kt & 7;
    const int g_own = kt >> 3;
    const int b_cell = bb * 8 + b_own;
    unsigned* gflags = flags + bb * NGW;

    // ---- W_hh slice into registers (once) ----
    float4 Wv[4][4];
#pragma unroll
    for (int g = 0; g < 4; ++g) {
        const float* wp = Whh + (size_t)(g * 512 + j_cell) * 512 + kt * 16;
#pragma unroll
        for (int q = 0; q < 4; ++q) Wv[g][q] = *(const float4*)(wp + q * 4);
    }

    float c = ccar[b_cell * 512 + j_cell];
    if (g_own == 0)  // publish slot-0 h
        st_agent_f32(&hbuf[b_cell * 512 + j_cell], hcar[b_cell * 512 + j_cell]);

    // prefetch xW for t=0 (plain cached load; xW written by a prior dispatch)
    float xw_cur = xW[b_cell * 2048 + g_own * 512 + j_cell];

    // ---- barrier 0: publish slot-0 h ----
    __syncthreads();  // drains the agent stores (compiler-tracked)
    if (tid == 0) st_agent_u32(&gflags[js], (unsigned)(fbase + 1));
    if (tid < 64) {
        const unsigned tgt = (unsigned)(fbase + 1);
        int guard = 0;
        for (;;) {
            unsigned v = ld_agent_u32(&gflags[tid & (NGW - 1)]);
            if (__all((int)(v >= tgt))) break;
            __builtin_amdgcn_s_sleep(2);
            if (++guard > (1 << 18)) break;  // failsafe -> visible absmax failure
        }
    }
    __syncthreads();

    for (int t = 0; t < TC; ++t) {
        const int rd = full_seq ? t : (t & 1);
        const int wr = full_seq ? (t + 1) : ((t + 1) & 1);
        const float* hrd = hbuf + (size_t)rd * 32768;

        // ---- stage h tile [8b][512k] into LDS (f4-slot swizzled), 4 f2/thread ----
#pragma unroll
        for (int i = 0; i < 4; ++i) {
            int fid = tid + i * 512;  // 0..2047
            int b = fid >> 8, k2 = fid & 255;
            unsigned long long v =
                ld_agent_u64((const unsigned long long*)&hrd[(bb * 8 + b) * 512 + k2 * 2]);
            int s4 = b * 128 + (k2 >> 1);
            int ph = s4 ^ ((s4 >> 4) & 7);
            *(unsigned long long*)&h4[ph * 4 + (k2 & 1) * 2] = v;
        }
        __syncthreads();

        // prefetch next step's xW now — its LLC latency hides under the MACs
        const int tn = (t + 1 < TC) ? (t + 1) : t;
        const float xw_next = xW[(size_t)tn * 131072 + b_cell * 2048 + g_own * 512 + j_cell];

        // ---- MACs: acc[g*8+b] += Wv[g][q] . h[b][kt*16+q*4 ..] ----
        float acc[32];
#pragma unroll
        for (int v = 0; v < 32; ++v) acc[v] = 0.f;
#pragma unroll
        for (int q = 0; q < 4; ++q) {
#pragma unroll
            for (int b = 0; b < 8; ++b) {
                const int slot = b * 128 + kt * 4 + q;
                const float4 hv = *(const float4*)&h4[(slot ^ ((slot >> 4) & 7)) * 4];
#pragma unroll
                for (int g = 0; g < 4; ++g) {
                    acc[g * 8 + b] = fmaf(Wv[g][q].x, hv.x, acc[g * 8 + b]);
                    acc[g * 8 + b] = fmaf(Wv[g][q].y, hv.y, acc[g * 8 + b]);
                    acc[g * 8 + b] = fmaf(Wv[g][q].z, hv.z, acc[g * 8 + b]);
                    acc[g * 8 + b] = fmaf(Wv[g][q].w, hv.w, acc[g * 8 + b]);
                }
            }
        }

        // ---- 5-stage merge-exchange over kt; lane kt ends owning v = kt ----
        float v16[16];
#pragma unroll
        for (int i = 0; i < 16; ++i) {
            float hi = acc[i + 16], lo = acc[i];
            float keep = (kt & 16) ? hi : lo, send = (kt & 16) ? lo : hi;
            v16[i] = keep + __shfl_xor(send, 16);
        }
        float v8[8];
#pragma unroll
        for (int i = 0; i < 8; ++i) {
            float hi = v16[i + 8], lo = v16[i];
            float keep = (kt & 8) ? hi : lo, send = (kt & 8) ? lo : hi;
            v8[i] = keep + __shfl_xor(send, 8);
        }
        float v4a[4];
#pragma unroll
        for (int i = 0; i < 4; ++i) {
            float hi = v8[i + 4], lo = v8[i];
            float keep = (kt & 4) ? hi : lo, send = (kt & 4) ? lo : hi;
            v4a[i] = keep + __shfl_xor(send, 4);
        }
        float v2a[2];
#pragma unroll
        for (int i = 0; i < 2; ++i) {
            float hi = v4a[i + 2], lo = v4a[i];
            float keep = (kt & 2) ? hi : lo, send = (kt & 2) ? lo : hi;
            v2a[i] = keep + __shfl_xor(send, 2);
        }
        float s;
        {
            float hi = v2a[1], lo = v2a[0];
            float keep = (kt & 1) ? hi : lo, send = (kt & 1) ? lo : hi;
            s = keep + __shfl_xor(send, 1);
        }

        // gather 4 gate pre-acts for (j_cell, b_own) — width-32 segments
        const float sfull = s + xw_cur;
        const float p0 = __shfl(sfull, 0 + b_own, 32);
        const float p1 = __shfl(sfull, 8 + b_own, 32);
        const float p2 = __shfl(sfull, 16 + b_own, 32);
        const float p3 = __shfl(sfull, 24 + b_own, 32);

        const float gi = sigmoidf_(p0);
        const float gf = sigmoidf_(p1);
        const float gg = tanhf_(p2);
        const float go = sigmoidf_(p3);
        c = gf * c + gi * gg;  // identical across the 4 g-replica lanes
        const float hn = go * tanhf_(c);
        if (g_own == 0) {
            st_agent_f32(&hbuf[(size_t)wr * 32768 + b_cell * 512 + j_cell], hn);
            if (t == TC - 1) {  // carries for next chunk (cross-dispatch)
                hcar[b_cell * 512 + j_cell] = hn;
                ccar[b_cell * 512 + j_cell] = c;
            }
        }
        xw_cur = xw_next;

        // ---- publish h(t+1) + wait for group (skip after last step) ----
        if (t < TC - 1) {
            __syncthreads();  // drains the agent h-stores (compiler-tracked)
            if (tid == 0) st_agent_u32(&gflags[js], (unsigned)(fbase + t + 2));
            if (tid < 64) {
                const unsigned tgt = (unsigned)(fbase + t + 2);
                int guard = 0;
                for (;;) {
                    unsigned v = ld_agent_u32(&gflags[tid & (NGW - 1)]);
                    if (__all((int)(v >= tgt))) break;
                    __builtin_amdgcn_s_sleep(2);
                    if (++guard > (1 << 18)) break;  // failsafe
                }
            }
            __syncthreads();
        }
    }
}

// ---------------- FC head ----------------
__global__ __launch_bounds__(256) void fc_kernel(
    const float* __restrict__ h, const float* __restrict__ Wfc,
    const float* __restrict__ bfc, float* __restrict__ out) {
    int gid = blockIdx.x * 256 + threadIdx.x;  // 0..8191
    int b = gid >> 7, cc = gid & 127;
    const float* hr = h + b * 512;
    const float* wr = Wfc + cc * 512;
    float s = 0.f;
#pragma unroll 4
    for (int k = 0; k < 512; k += 4) {
        float4 hv = *(const float4*)(hr + k);
        float4 wv = *(const float4*)(wr + k);
        s += hv.x * wv.x + hv.y * wv.y + hv.z * wv.z + hv.w * wv.w;
    }
    out[gid] = s + bfc[cc];
}

// ---------------- launch ----------------
extern "C" void kernel_launch(void* const* d_in, const int* in_sizes, int n_in,
                              void* d_out, int out_size, void* d_ws, size_t ws_size,
                              hipStream_t stream) {
    const float* x = (const float*)d_in[0];
    const float* h0 = (const float*)d_in[1];
    const float* c0 = (const float*)d_in[2];
    const float* Wih0 = (const float*)d_in[3];
    const float* Whh0 = (const float*)d_in[4];
    const float* bih0 = (const float*)d_in[5];
    const float* bhh0 = (const float*)d_in[6];
    const float* Wih1 = (const float*)d_in[7];
    const float* Whh1 = (const float*)d_in[8];
    const float* bih1 = (const float*)d_in[9];
    const float* bhh1 = (const float*)d_in[10];
    const float* Wfc = (const float*)d_in[11];
    const float* bfc = (const float*)d_in[12];

    // workspace layout (~43 MB total)
    char* ws = (char*)d_ws;
    size_t off = 0;
    float* xWc = (float*)(ws + off); off += (size_t)TC * 64 * 2048 * 4;      // 33,554,432
    float* hseqc = (float*)(ws + off); off += (size_t)(TC + 1) * 32768 * 4;  //  8,519,680
    float* hpp = (float*)(ws + off); off += 2 * 32768 * 4;                   //    262,144
    float* hcar0 = (float*)(ws + off); off += 32768 * 4;
    float* ccar0 = (float*)(ws + off); off += 32768 * 4;
    float* hcar1 = (float*)(ws + off); off += 32768 * 4;
    float* ccar1 = (float*)(ws + off); off += 32768 * 4;
    float* bs0 = (float*)(ws + off); off += 2048 * 4;
    float* bs1 = (float*)(ws + off); off += 2048 * 4;
    unsigned* flagsA = (unsigned*)(ws + off); off += 8 * NGW * 4;  // [bb][js]
    unsigned* flagsB = (unsigned*)(ws + off); off += 8 * NGW * 4;

    prep_bias<<<8, 256, 0, stream>>>(bih0, bhh0, bih1, bhh1, bs0, bs1);
    init_carry<<<128, 256, 0, stream>>>(h0, c0, hcar0, ccar0, hcar1, ccar1);
    hipMemsetAsync(flagsA, 0, 2 * 8 * NGW * 4, stream);

    const dim3 gg(16, 32);
    for (int k = 0; k < NCHUNK; ++k) {
        // layer-0 input GEMM for chunk k: xWc[t][b][2048]
        gemm_xw<256><<<gg, 256, 0, stream>>>(x, Wih0, bs0, xWc, 0, k * TC);
        // layer-0 recurrence over chunk; writes hseqc slots 1..TC
        lstm_rec<<<256, 512, 0, stream>>>(xWc, Whh0, hcar0, ccar0, hseqc, 1, flagsA, k * TC);
        // layer-1 input GEMM from hseqc slots 1..TC (rows already [t][b])
        gemm_xw<512><<<gg, 256, 0, stream>>>(hseqc + 32768, Wih1, bs1, xWc, 1, 0);
        // layer-1 recurrence (ping-pong h)
        lstm_rec<<<256, 512, 0, stream>>>(xWc, Whh1, hcar1, ccar1, hpp, 0, flagsB, k * TC);
    }
    // FC on final layer-1 hidden state (carry buffer)
    fc_kernel<<<32, 256, 0, stream>>>(hcar1, Wfc, bfc, (float*)d_out);
}